// Round 5
// baseline (220.562 us; speedup 1.0000x reference)
//
#include <hip/hip_runtime.h>

#define H 4096
#define W 4096
#define TC 4               // cols per thread
#define TPB 256
#define STRIP (TPB*TC)     // 1024 cols per block
#define NSTRIP (W/STRIP)   // 4
#define NBLK (NSTRIP*H)    // 16384 blocks, 1 output row each
#define LN2 0.69314718055994531f

// One output row per block-row: depth-1 dependence (load 3x4 window, compute).
// Latency hidden by TLP (8 waves/SIMD at <=64 VGPR), not register pipelining.
template<bool INTERIOR>
__device__ __forceinline__ float row_loss(const float* __restrict__ sp,
                                          const float* __restrict__ op,
                                          int r, bool eL, bool eR, int lane) {
  float s[3][TC], o[3][TC];
  float sl[3], ol[3], sr[3], orr[3];

  #pragma unroll
  for (int j = 0; j < 3; ++j) {          // rows r-1, r, r+1 — all loads independent
    const long off = (long)(j - 1) * W;
    const bool v = INTERIOR || ((r - 1 + j) >= 0 && (r - 1 + j) < H);
    if (v) {
      const float4 a = *reinterpret_cast<const float4*>(sp + off);
      const float4 b = *reinterpret_cast<const float4*>(op + off);
      s[j][0] = a.x; s[j][1] = a.y; s[j][2] = a.z; s[j][3] = a.w;
      o[j][0] = b.x; o[j][1] = b.y; o[j][2] = b.z; o[j][3] = b.w;
      sl[j]  = eL ? sp[off - 1]  : 0.f;   // exec-masked: lane 0 only
      ol[j]  = eL ? op[off - 1]  : 0.f;
      sr[j]  = eR ? sp[off + TC] : 0.f;   // lane 63 only
      orr[j] = eR ? op[off + TC] : 0.f;
    } else {
      #pragma unroll
      for (int k = 0; k < TC; ++k) { s[j][k] = 0.f; o[j][k] = 0.f; }
      sl[j] = ol[j] = sr[j] = orr[j] = 0.f;
    }
  }

  float cs[TC], co[TC];
  #pragma unroll
  for (int k = 0; k < TC; ++k) {
    cs[k] = s[0][k] + s[1][k] + s[2][k];
    co[k] = o[0][k] + o[1][k] + o[2][k];
  }

  // halo column sums from neighbor lanes (wave-internal); lanes 0/63 use globals
  float csL = __shfl_up(cs[TC-1], 1, 64);  if (lane == 0)  csL = sl[0] + sl[1] + sl[2];
  float coL = __shfl_up(co[TC-1], 1, 64);  if (lane == 0)  coL = ol[0] + ol[1] + ol[2];
  float csR = __shfl_down(cs[0], 1, 64);   if (lane == 63) csR = sr[0] + sr[1] + sr[2];
  float coR = __shfl_down(co[0], 1, 64);   if (lane == 63) coR = orr[0] + orr[1] + orr[2];

  float acc = 0.f;
  #pragma unroll
  for (int k = 0; k < TC; ++k) {
    const float cl  = (k == 0)    ? csL : cs[k-1];
    const float cr  = (k == TC-1) ? csR : cs[k+1];
    const float nsS = cl + cs[k] + cr - s[1][k];     // in-bounds 8-neighbor sum (seg)
    const float col = (k == 0)    ? coL : co[k-1];
    const float cor = (k == TC-1) ? coR : co[k+1];
    const float nsO = col + co[k] + cor - o[1][k];   // in-bounds 8-neighbor sum (out)
    const float w1 = 9.f - nsS;                      // sig_seg_1
    const float m0 = 1.f + nsO;                      // sig_out_0
    const float sv = s[1][k], ov = o[1][k];
    acc += w1 * sv * __log2f(ov + 1e-5f) + m0 * (1.f - sv) * __log2f(1.00001f - ov);
  }
  return acc;
}

__global__ __launch_bounds__(TPB)
void wbce_kernel(const float* __restrict__ outp, const float* __restrict__ segp,
                 float* __restrict__ dsum) {
  // XCD-chunk swizzle (bijective: NBLK % 8 == 0): each XCD gets a contiguous
  // run of rows so the 3x vertical row re-read is served from its own L2.
  const int p = blockIdx.x;
  const int logical = (p & 7) * (NBLK / 8) + (p >> 3);
  const int strip = logical & (NSTRIP - 1);
  const int r     = logical >> 2;            // NSTRIP == 4
  const int t     = threadIdx.x;
  const int c0    = strip * STRIP + t * TC;
  const int lane  = t & 63;
  const bool eL   = (lane == 0)  && (c0 > 0);
  const bool eR   = (lane == 63) && (c0 + TC < W);

  const float* sp = segp + (size_t)r * W + c0;
  const float* op = outp + (size_t)r * W + c0;

  float acc;
  if (r > 0 && r < H - 1) acc = row_loss<true >(sp, op, r, eL, eR, lane);
  else                    acc = row_loss<false>(sp, op, r, eL, eR, lane);

  // wave reduce (64 lanes)
  #pragma unroll
  for (int off = 32; off > 0; off >>= 1) acc += __shfl_down(acc, off, 64);

  __shared__ float wsum[TPB / 64];
  if ((t & 63) == 0) wsum[t >> 6] = acc;
  __syncthreads();
  if (t == 0) {
    const float ssum = wsum[0] + wsum[1] + wsum[2] + wsum[3];
    atomicAdd(dsum, ssum * (-LN2 / ((float)H * (float)W)));  // loss = -mean, log2->ln
  }
}

extern "C" void kernel_launch(void* const* d_in, const int* in_sizes, int n_in,
                              void* d_out, int out_size, void* d_ws, size_t ws_size,
                              hipStream_t stream) {
  const float* outp = (const float*)d_in[0];  // out_image
  const float* segp = (const float*)d_in[1];  // segment_image
  float* o = (float*)d_out;
  hipMemsetAsync(o, 0, sizeof(float), stream);   // graph-capturable; re-zero every call
  wbce_kernel<<<dim3(NBLK), TPB, 0, stream>>>(outp, segp, o);
}

// Round 6
// 33.931 us; speedup vs baseline: 6.5003x; 6.5003x over previous
//
#include <hip/hip_runtime.h>

#define H 4096
#define W 4096
#define R 8              // rows per block
#define TC 4             // cols per thread
#define TPB 256
#define STRIP (TPB*TC)   // 1024 cols per block
#define NSTRIP (W/STRIP) // 4
#define NBAND (H/R)      // 512
#define NBLK (NSTRIP*NBAND) // 2048 partials

__global__ __launch_bounds__(TPB)
void wbce_kernel(const float* __restrict__ outp, const float* __restrict__ segp,
                 float* __restrict__ partial) {
  const int t     = threadIdx.x;
  const int strip = blockIdx.x;
  const int r0    = blockIdx.y * R;
  const int c0    = strip * STRIP + t * TC;
  const int cL    = c0 - 1;
  const int cR    = c0 + TC;
  const bool lv   = (cL >= 0);
  const bool rv   = (cR < W);

  // rolling 3-row window: interior TC columns (vector) + 2 halo columns (scalar)
  float sa[TC], sb[TC], sc[TC];
  float oa[TC], ob[TC], oc[TC];
  float sLa, sLb, sLc, sRa, sRb, sRc;
  float oLa, oLb, oLc, oRa, oRb, oRc;

  auto loadrow = [&](int ri, float* sv, float* ov,
                     float& sl, float& sr, float& ol, float& orr) {
    if (ri >= 0 && ri < H) {
      const size_t base = (size_t)ri * W;
      const float4 fs = *reinterpret_cast<const float4*>(segp + base + c0);
      const float4 fo = *reinterpret_cast<const float4*>(outp + base + c0);
      sv[0] = fs.x; sv[1] = fs.y; sv[2] = fs.z; sv[3] = fs.w;
      ov[0] = fo.x; ov[1] = fo.y; ov[2] = fo.z; ov[3] = fo.w;
      sl  = lv ? segp[base + cL] : 0.f;
      ol  = lv ? outp[base + cL] : 0.f;
      sr  = rv ? segp[base + cR] : 0.f;
      orr = rv ? outp[base + cR] : 0.f;
    } else {
      sv[0] = sv[1] = sv[2] = sv[3] = 0.f;
      ov[0] = ov[1] = ov[2] = ov[3] = 0.f;
      sl = sr = ol = orr = 0.f;
    }
  };

  loadrow(r0 - 1, sa, oa, sLa, oLa, sRa, oRa);
  loadrow(r0,     sb, ob, sLb, oLb, sRb, oRb);

  float acc = 0.f;

  #pragma unroll
  for (int i = 0; i < R; ++i) {
    const int r = r0 + i;
    loadrow(r + 1, sc, oc, sLc, oLc, sRc, oRc);

    float cs[TC], co[TC];
    #pragma unroll
    for (int k = 0; k < TC; ++k) {
      cs[k] = sa[k] + sb[k] + sc[k];
      co[k] = oa[k] + ob[k] + oc[k];
    }
    const float csL = sLa + sLb + sLc;
    const float csR = sRa + sRb + sRc;
    const float coL = oLa + oLb + oLc;
    const float coR = oRa + oRb + oRc;

    #pragma unroll
    for (int k = 0; k < TC; ++k) {
      const float cl  = (k == 0)    ? csL : cs[k-1];
      const float cr  = (k == TC-1) ? csR : cs[k+1];
      const float nsS = cl + cs[k] + cr - sb[k];     // 8-neighbor sum of seg
      const float col = (k == 0)    ? coL : co[k-1];
      const float cor = (k == TC-1) ? coR : co[k+1];
      const float nsO = col + co[k] + cor - ob[k];   // 8-neighbor sum of out
      const float w1 = 9.f - nsS;                    // sig_seg_1
      const float m0 = 1.f + nsO;                    // sig_out_0
      const float s = sb[k], o = ob[k];
      acc += w1 * s * __logf(o + 1e-5f) + m0 * (1.f - s) * __logf(1.f - o + 1e-5f);
    }

    #pragma unroll
    for (int k = 0; k < TC; ++k) {
      sa[k] = sb[k]; sb[k] = sc[k];
      oa[k] = ob[k]; ob[k] = oc[k];
    }
    sLa = sLb; sLb = sLc;  sRa = sRb; sRb = sRc;
    oLa = oLb; oLb = oLc;  oRa = oRb; oRb = oRc;
  }

  // wave reduce (64 lanes)
  #pragma unroll
  for (int off = 32; off > 0; off >>= 1) acc += __shfl_down(acc, off, 64);

  __shared__ float wsum[TPB / 64];
  if ((t & 63) == 0) wsum[t >> 6] = acc;
  __syncthreads();
  if (t == 0) {
    // NO atomic: plain per-block partial store (serialized single-address
    // atomics cost ~13 ns each => 27 us floor at 2048 blocks).
    partial[blockIdx.y * NSTRIP + blockIdx.x] = wsum[0] + wsum[1] + wsum[2] + wsum[3];
  }
}

__global__ __launch_bounds__(TPB)
void reduce_kernel(const float* __restrict__ partial, float* __restrict__ out) {
  const int t = threadIdx.x;
  float a = 0.f;
  #pragma unroll
  for (int i = 0; i < NBLK / (TPB * 4); ++i) {   // 2048 floats = 512 float4, 256 thr x 2
    const float4 v = reinterpret_cast<const float4*>(partial)[t + i * TPB];
    a += v.x + v.y + v.z + v.w;
  }
  #pragma unroll
  for (int off = 32; off > 0; off >>= 1) a += __shfl_down(a, off, 64);
  __shared__ float ws[TPB / 64];
  if ((t & 63) == 0) ws[t >> 6] = a;
  __syncthreads();
  if (t == 0)
    out[0] = (ws[0] + ws[1] + ws[2] + ws[3]) * (-1.0f / ((float)H * (float)W));
}

extern "C" void kernel_launch(void* const* d_in, const int* in_sizes, int n_in,
                              void* d_out, int out_size, void* d_ws, size_t ws_size,
                              hipStream_t stream) {
  const float* outp = (const float*)d_in[0];  // out_image
  const float* segp = (const float*)d_in[1];  // segment_image
  float* part = (float*)d_ws;                 // 2048 floats of scratch
  float* o = (float*)d_out;
  wbce_kernel<<<dim3(NSTRIP, NBAND), TPB, 0, stream>>>(outp, segp, part);
  reduce_kernel<<<1, TPB, 0, stream>>>(part, o);
}

// Round 7
// 32.556 us; speedup vs baseline: 6.7748x; 1.0422x over previous
//
#include <hip/hip_runtime.h>

#define H 4096
#define W 4096
#define R 8              // rows per block
#define TC 4             // cols per thread
#define TPB 256
#define STRIP (TPB*TC)   // 1024 cols per block
#define NSTRIP (W/STRIP) // 4
#define NBAND (H/R)      // 512
#define NBLK (NSTRIP*NBAND) // 2048 partials
#define LN2 0.69314718055994531f

// Rolling 3-row window, advancing-pointer addressing (1 add/ptr/row; halos fold
// into load immediates at -4B/+16B). Latency hidden by TLP at <=64 VGPR.
template<bool INTERIOR>
__device__ __forceinline__ float band_loss(const float* __restrict__ sp0,
                                           const float* __restrict__ op0,
                                           int r0, bool lv, bool rv) {
  float sa[TC], sb[TC], sc[TC];
  float oa[TC], ob[TC], oc[TC];
  float sLa, sLb, sLc, sRa, sRb, sRc;
  float oLa, oLb, oLc, oRa, oRb, oRc;

  const float* sp = sp0 - W;   // row r0-1
  const float* op = op0 - W;

  auto loadrow = [&](bool valid, float* sv, float* ov,
                     float& sl, float& sr, float& ol, float& orr) {
    if (valid) {
      const float4 fs = *reinterpret_cast<const float4*>(sp);
      const float4 fo = *reinterpret_cast<const float4*>(op);
      sv[0] = fs.x; sv[1] = fs.y; sv[2] = fs.z; sv[3] = fs.w;
      ov[0] = fo.x; ov[1] = fo.y; ov[2] = fo.z; ov[3] = fo.w;
      sl  = lv ? sp[-1] : 0.f;    // same vaddr, imm offset -4
      ol  = lv ? op[-1] : 0.f;
      sr  = rv ? sp[TC] : 0.f;    // imm offset +16
      orr = rv ? op[TC] : 0.f;
    } else {
      sv[0] = sv[1] = sv[2] = sv[3] = 0.f;
      ov[0] = ov[1] = ov[2] = ov[3] = 0.f;
      sl = sr = ol = orr = 0.f;
    }
  };

  loadrow(INTERIOR || (r0 - 1 >= 0), sa, oa, sLa, sRa, oLa, oRa);
  sp += W; op += W;
  loadrow(true, sb, ob, sLb, sRb, oLb, oRb);

  float acc = 0.f;

  #pragma unroll
  for (int i = 0; i < R; ++i) {
    sp += W; op += W;
    loadrow(INTERIOR || (r0 + i + 1 < H), sc, oc, sLc, sRc, oLc, oRc);

    float cs[TC], co[TC];
    #pragma unroll
    for (int k = 0; k < TC; ++k) {
      cs[k] = sa[k] + sb[k] + sc[k];
      co[k] = oa[k] + ob[k] + oc[k];
    }
    const float csL = sLa + sLb + sLc;
    const float csR = sRa + sRb + sRc;
    const float coL = oLa + oLb + oLc;
    const float coR = oRa + oRb + oRc;

    #pragma unroll
    for (int k = 0; k < TC; ++k) {
      const float cl  = (k == 0)    ? csL : cs[k-1];
      const float cr  = (k == TC-1) ? csR : cs[k+1];
      const float nsS = cl + cs[k] + cr - sb[k];     // 8-neighbor sum of seg
      const float col = (k == 0)    ? coL : co[k-1];
      const float cor = (k == TC-1) ? coR : co[k+1];
      const float nsO = col + co[k] + cor - ob[k];   // 8-neighbor sum of out
      const float w1 = 9.f - nsS;                    // sig_seg_1
      const float m0 = 1.f + nsO;                    // sig_out_0
      const float s = sb[k], o = ob[k];
      // log2 units; one LN2 scale at the very end (reduce kernel)
      acc += w1 * s * __log2f(o + 1e-5f) + m0 * (1.f - s) * __log2f(1.00001f - o);
    }

    #pragma unroll
    for (int k = 0; k < TC; ++k) {
      sa[k] = sb[k]; sb[k] = sc[k];
      oa[k] = ob[k]; ob[k] = oc[k];
    }
    sLa = sLb; sLb = sLc;  sRa = sRb; sRb = sRc;
    oLa = oLb; oLb = oLc;  oRa = oRb; oRb = oRc;
  }
  return acc;
}

__global__ __launch_bounds__(TPB)
void wbce_kernel(const float* __restrict__ outp, const float* __restrict__ segp,
                 float* __restrict__ partial) {
  const int t     = threadIdx.x;
  const int strip = blockIdx.x;
  const int band  = blockIdx.y;
  const int r0    = band * R;
  const int c0    = strip * STRIP + t * TC;
  const bool lv   = (c0 > 0);
  const bool rv   = (c0 + TC < W);

  const float* sp0 = segp + (size_t)r0 * W + c0;
  const float* op0 = outp + (size_t)r0 * W + c0;

  float acc;
  if (band > 0 && band < NBAND - 1) acc = band_loss<true >(sp0, op0, r0, lv, rv);
  else                              acc = band_loss<false>(sp0, op0, r0, lv, rv);

  // wave reduce (64 lanes)
  #pragma unroll
  for (int off = 32; off > 0; off >>= 1) acc += __shfl_down(acc, off, 64);

  __shared__ float wsum[TPB / 64];
  if ((t & 63) == 0) wsum[t >> 6] = acc;
  __syncthreads();
  if (t == 0)
    partial[band * NSTRIP + strip] = wsum[0] + wsum[1] + wsum[2] + wsum[3];
}

__global__ __launch_bounds__(64)
void reduce_kernel(const float* __restrict__ partial, float* __restrict__ out) {
  const int t = threadIdx.x;
  float a = 0.f;
  #pragma unroll
  for (int i = 0; i < NBLK / (64 * 4); ++i) {     // 8 independent float4 loads
    const float4 v = reinterpret_cast<const float4*>(partial)[t + i * 64];
    a += v.x + v.y + v.z + v.w;
  }
  #pragma unroll
  for (int off = 32; off > 0; off >>= 1) a += __shfl_down(a, off, 64);
  if (t == 0)
    out[0] = a * (-LN2 / ((float)H * (float)W));  // log2 -> ln, -mean
}

extern "C" void kernel_launch(void* const* d_in, const int* in_sizes, int n_in,
                              void* d_out, int out_size, void* d_ws, size_t ws_size,
                              hipStream_t stream) {
  const float* outp = (const float*)d_in[0];  // out_image
  const float* segp = (const float*)d_in[1];  // segment_image
  float* part = (float*)d_ws;                 // 2048 floats of scratch
  float* o = (float*)d_out;
  wbce_kernel<<<dim3(NSTRIP, NBAND), TPB, 0, stream>>>(outp, segp, part);
  reduce_kernel<<<1, 64, 0, stream>>>(part, o);
}